// Round 1
// baseline (2134.584 us; speedup 1.0000x reference)
//
#include <hip/hip_runtime.h>
#include <hip/hip_bf16.h>

#define DEVINL __device__ __forceinline__

typedef __attribute__((ext_vector_type(8))) short s8v;   // 8 x bf16 bits (4 VGPR)
typedef __attribute__((ext_vector_type(4))) float f4v;   // MFMA accum

using bf16 = __hip_bfloat16;

DEVINL unsigned short f2bu(float f) {
  bf16 h = __float2bfloat16(f);  // RNE
  return *reinterpret_cast<unsigned short*>(&h);
}

DEVINL void gload16(const void* g, void* l) {
  // async global->LDS, 16B per lane; LDS dest = wave-uniform base + lane*16
  __builtin_amdgcn_global_load_lds((const __attribute__((address_space(1))) void*)g,
                                   (__attribute__((address_space(3))) void*)l, 16, 0, 0);
}

// ---------------- conversion kernels ----------------
__global__ void k_f32_to_bf16(const float* __restrict__ x, unsigned short* __restrict__ y, long n4) {
  long i = (long)blockIdx.x * blockDim.x + threadIdx.x;
  if (i >= n4) return;
  float4 v = ((const float4*)x)[i];
  ushort4 o;
  o.x = f2bu(v.x); o.y = f2bu(v.y); o.z = f2bu(v.z); o.w = f2bu(v.w);
  ((ushort4*)y)[i] = o;
}

// W [rows][cols] fp32 -> Wt [cols][rows] bf16   (weights become B^T, contiguous-K)
__global__ void k_transpose_bf16(const float* __restrict__ W, unsigned short* __restrict__ Wt,
                                 int rows, int cols) {
  __shared__ float tile[32][33];
  const int tx = threadIdx.x, ty = threadIdx.y;
  const int c0 = blockIdx.x * 32, r0 = blockIdx.y * 32;
  #pragma unroll
  for (int i = ty; i < 32; i += 8)
    tile[i][tx] = W[(long)(r0 + i) * cols + (c0 + tx)];
  __syncthreads();
  #pragma unroll
  for (int i = ty; i < 32; i += 8)
    Wt[(long)(c0 + i) * rows + (r0 + tx)] = f2bu(tile[tx][i]);
}

// ---------------- GEMM: C[M][N] = A[M][K] @ Bt[N][K]^T ----------------
// 128x128 tile, BK=64, 4 waves (2x2 of 64x64), mfma_f32_16x16x32_bf16.
// EPI=1: C = bf16(relu(acc + bias[col]))          (layer 1/2 producing h)
// EPI=2: oacc[row] += sum_col relu(acc+bias)*w3   (fused layer-3 dot)
template<int EPI>
__global__ __launch_bounds__(256, 2)
void k_gemm_bt(const unsigned short* __restrict__ A, const unsigned short* __restrict__ Bt,
               unsigned short* __restrict__ C, const float* __restrict__ bias,
               const float* __restrict__ w3, float* __restrict__ oacc,
               int N, int K) {
  __shared__ unsigned short As[128 * 64];
  __shared__ unsigned short Bs[128 * 64];
  const int tid = threadIdx.x;
  const int w = tid >> 6;
  const int lane = tid & 63;
  const int bn = blockIdx.x, bm = blockIdx.y;   // x = col-block (16) for A-panel L2 reuse
  const int wm = (w >> 1) * 64, wn = (w & 1) * 64;

  f4v acc[4][4];
  #pragma unroll
  for (int a = 0; a < 4; ++a)
    #pragma unroll
    for (int b = 0; b < 4; ++b)
      #pragma unroll
      for (int r = 0; r < 4; ++r) acc[a][b][r] = 0.f;

  // staging: each wave stages 32 rows of A and 32 rows of Bt (4 x 1KB instrs each)
  const int r_in = lane >> 3;          // 0..7 row within 8-row chunk
  const int c_in = (lane & 7) * 8;     // bf16 element offset within row chunk
  const unsigned short* Ag = A + ((long)bm * 128 + w * 32 + r_in) * K + c_in;
  const unsigned short* Bg = Bt + ((long)bn * 128 + w * 32 + r_in) * K + c_in;
  char* AsB = (char*)As + w * 32 * 128;  // 128B per row of 64 bf16
  char* BsB = (char*)Bs + w * 32 * 128;

  const int row_a = wm + (lane & 15);
  const int row_b = wn + (lane & 15);
  const int kreg = (lane >> 4) * 8;

  for (int kt = 0; kt < K; kt += 64) {
    __syncthreads();                       // previous tile's MFMA reads done
    #pragma unroll
    for (int t = 0; t < 4; ++t) {
      gload16(Ag + (long)t * 8 * K, AsB + t * 1024);
      gload16(Bg + (long)t * 8 * K, BsB + t * 1024);
    }
    Ag += 64; Bg += 64;
    __syncthreads();                       // staging visible (compiler drains vmcnt)
    #pragma unroll
    for (int kk = 0; kk < 2; ++kk) {
      s8v af[4], bf_[4];
      const int kb = kk * 32 + kreg;
      #pragma unroll
      for (int i = 0; i < 4; ++i) {
        af[i]  = *(const s8v*)&As[(row_a + i * 16) * 64 + kb];
        bf_[i] = *(const s8v*)&Bs[(row_b + i * 16) * 64 + kb];
      }
      #pragma unroll
      for (int mi = 0; mi < 4; ++mi)
        #pragma unroll
        for (int ni = 0; ni < 4; ++ni)
          acc[mi][ni] = __builtin_amdgcn_mfma_f32_16x16x32_bf16(af[mi], bf_[ni], acc[mi][ni], 0, 0, 0);
    }
  }

  // C/D layout (m89-verified): col = lane&15, row = (lane>>4)*4 + reg
  const int crow0 = wm + (lane >> 4) * 4;
  const int ccol0 = wn + (lane & 15);
  if (EPI == 1) {
    #pragma unroll
    for (int mi = 0; mi < 4; ++mi)
      #pragma unroll
      for (int ni = 0; ni < 4; ++ni) {
        const int col = bn * 128 + ccol0 + ni * 16;
        const float bb = bias[col];
        #pragma unroll
        for (int r = 0; r < 4; ++r) {
          const long row = (long)bm * 128 + crow0 + mi * 16 + r;
          float v = acc[mi][ni][r] + bb;
          v = v > 0.f ? v : 0.f;
          C[row * N + col] = f2bu(v);
        }
      }
  } else {
    #pragma unroll
    for (int mi = 0; mi < 4; ++mi)
      #pragma unroll
      for (int r = 0; r < 4; ++r) {
        float s = 0.f;
        #pragma unroll
        for (int ni = 0; ni < 4; ++ni) {
          const int col = bn * 128 + ccol0 + ni * 16;
          float v = acc[mi][ni][r] + bias[col];
          v = v > 0.f ? v : 0.f;
          s += v * w3[col];
        }
        // reduce over the 16 lanes sharing this row (xor within quarter-wave)
        s += __shfl_xor(s, 1, 64);
        s += __shfl_xor(s, 2, 64);
        s += __shfl_xor(s, 4, 64);
        s += __shfl_xor(s, 8, 64);
        if ((lane & 15) == 0) {
          const long row = (long)bm * 128 + crow0 + mi * 16 + r;
          atomicAdd(&oacc[row], s);
        }
      }
  }
}

// ---------------- segment ops ----------------
// segment_ids may be int64 (x64 jax) or int32. Detect: word[N-1] is the high
// half of an int64 element (== 0) or the last sorted int32 id (~4095, != 0).
__global__ void k_detect(const int* __restrict__ seg, int n, int* __restrict__ flag) {
  if (blockIdx.x == 0 && threadIdx.x == 0) flag[0] = (seg[n - 1] == 0) ? 1 : 0;
}

__global__ void k_segsum(const float* __restrict__ oacc, const float* __restrict__ wacc,
                         const int* __restrict__ seg, const int* __restrict__ flag,
                         const float* __restrict__ ob3, const float* __restrict__ wb3,
                         float* __restrict__ osum, float* __restrict__ wsum, int n) {
  int i = blockIdx.x * blockDim.x + threadIdx.x;
  if (i >= n) return;
  int s = flag[0] ? seg[2 * i] : seg[i];
  atomicAdd(&osum[s], oacc[i] + ob3[0]);
  atomicAdd(&wsum[s], wacc[i] + wb3[0]);
}

__global__ void k_final(const float* __restrict__ oacc, const float* __restrict__ wacc,
                        const int* __restrict__ seg, const int* __restrict__ flag,
                        const float* __restrict__ ob3, const float* __restrict__ wb3,
                        const float* __restrict__ osum, const float* __restrict__ wsum,
                        float* __restrict__ out, int n) {
  int i = blockIdx.x * blockDim.x + threadIdx.x;
  if (i >= n) return;
  int s = flag[0] ? seg[2 * i] : seg[i];
  float o = oacc[i] + ob3[0];
  float ww = wacc[i] + wb3[0];
  out[i] = o - ww * (osum[s] / wsum[s]);
}

extern "C" void kernel_launch(void* const* d_in, const int* in_sizes, int n_in,
                              void* d_out, int out_size, void* d_ws, size_t ws_size,
                              hipStream_t stream) {
  constexpr int NA = 65536, D = 1024, H = 2048, M = 4096;
  const float* hidden = (const float*)d_in[0];
  const float* fW1 = (const float*)d_in[1];
  const float* fb1 = (const float*)d_in[2];
  const float* fW2 = (const float*)d_in[3];
  const float* fb2 = (const float*)d_in[4];
  const float* fW3 = (const float*)d_in[5];
  const float* fb3 = (const float*)d_in[6];
  const float* wW1 = (const float*)d_in[7];
  const float* wb1 = (const float*)d_in[8];
  const float* wW2 = (const float*)d_in[9];
  const float* wb2 = (const float*)d_in[10];
  const float* wW3 = (const float*)d_in[11];
  const float* wb3 = (const float*)d_in[12];
  const int* seg = (const int*)d_in[13];
  float* out = (float*)d_out;

  char* ws = (char*)d_ws;
  size_t off = 0;
  auto alloc = [&](size_t bytes) { char* p = ws + off; off += (bytes + 255) & ~(size_t)255; return p; };
  unsigned short* hbf  = (unsigned short*)alloc((size_t)NA * D * 2);   // 128 MB
  unsigned short* w1tf = (unsigned short*)alloc((size_t)H * D * 2);
  unsigned short* w1tw = (unsigned short*)alloc((size_t)H * D * 2);
  unsigned short* w2tf = (unsigned short*)alloc((size_t)H * H * 2);
  unsigned short* w2tw = (unsigned short*)alloc((size_t)H * H * 2);
  unsigned short* h1   = (unsigned short*)alloc((size_t)NA * H * 2);   // 256 MB, reused by both branches
  float* oacc = (float*)alloc((size_t)NA * 4);
  float* wacc = (float*)alloc((size_t)NA * 4);
  float* osum = (float*)alloc((size_t)M * 4);
  float* wsum = (float*)alloc((size_t)M * 4);
  int* flag = (int*)alloc(256);

  // conversions (bf16 + weight transpose)
  k_f32_to_bf16<<<(int)((long)NA * D / 4 / 256), 256, 0, stream>>>(hidden, hbf, (long)NA * D / 4);
  dim3 tb(32, 8);
  k_transpose_bf16<<<dim3(H / 32, D / 32), tb, 0, stream>>>(fW1, w1tf, D, H);
  k_transpose_bf16<<<dim3(H / 32, D / 32), tb, 0, stream>>>(wW1, w1tw, D, H);
  k_transpose_bf16<<<dim3(H / 32, H / 32), tb, 0, stream>>>(fW2, w2tf, H, H);
  k_transpose_bf16<<<dim3(H / 32, H / 32), tb, 0, stream>>>(wW2, w2tw, H, H);

  // zero accumulators (oacc..wsum are contiguous in ws)
  hipMemsetAsync(oacc, 0, (size_t)((char*)flag - (char*)oacc), stream);
  k_detect<<<1, 64, 0, stream>>>(seg, NA, flag);

  // ffn branch
  k_gemm_bt<1><<<dim3(H / 128, NA / 128), 256, 0, stream>>>(hbf, w1tf, h1, fb1, nullptr, nullptr, H, D);
  k_gemm_bt<2><<<dim3(H / 128, NA / 128), 256, 0, stream>>>(h1, w2tf, nullptr, fb2, fW3, oacc, H, H);
  // weight branch (reuses h1)
  k_gemm_bt<1><<<dim3(H / 128, NA / 128), 256, 0, stream>>>(hbf, w1tw, h1, wb1, nullptr, nullptr, H, D);
  k_gemm_bt<2><<<dim3(H / 128, NA / 128), 256, 0, stream>>>(h1, w2tw, nullptr, wb2, wW3, wacc, H, H);

  // segment ratio + final
  k_segsum<<<NA / 256, 256, 0, stream>>>(oacc, wacc, seg, flag, fb3, wb3, osum, wsum, NA);
  k_final<<<NA / 256, 256, 0, stream>>>(oacc, wacc, seg, flag, fb3, wb3, osum, wsum, out, NA);
}

// Round 2
// 2040.874 us; speedup vs baseline: 1.0459x; 1.0459x over previous
//
#include <hip/hip_runtime.h>
#include <hip/hip_bf16.h>

#define DEVINL __device__ __forceinline__

typedef __attribute__((ext_vector_type(8))) short s8v;   // 8 x bf16 bits
typedef __attribute__((ext_vector_type(4))) float f4v;   // MFMA accum

using bf16 = __hip_bfloat16;
typedef unsigned short u16;

DEVINL u16 f2bu(float f) {
  bf16 h = __float2bfloat16(f);  // RNE
  return *reinterpret_cast<u16*>(&h);
}

DEVINL void gload16(const void* g, void* l) {
  // async global->LDS, 16B/lane; LDS dest = wave-uniform base + lane*16
  __builtin_amdgcn_global_load_lds((const __attribute__((address_space(1))) void*)g,
                                   (__attribute__((address_space(3))) void*)l, 16, 0, 0);
}

#define BAR()   __builtin_amdgcn_s_barrier()
#define LGKM0() asm volatile("s_waitcnt lgkmcnt(0)" ::: "memory")
#define VM(n)   asm volatile("s_waitcnt vmcnt(" #n ")" ::: "memory")

// ---------------- conversion kernels ----------------
__global__ void k_f32_to_bf16(const float* __restrict__ x, u16* __restrict__ y, long n4) {
  long i = (long)blockIdx.x * blockDim.x + threadIdx.x;
  if (i >= n4) return;
  float4 v = ((const float4*)x)[i];
  ushort4 o;
  o.x = f2bu(v.x); o.y = f2bu(v.y); o.z = f2bu(v.z); o.w = f2bu(v.w);
  ((ushort4*)y)[i] = o;
}

// W [rows][cols] fp32 -> Wt [cols][rows] bf16
__global__ void k_transpose_bf16(const float* __restrict__ W, u16* __restrict__ Wt,
                                 int rows, int cols) {
  __shared__ float tile[32][33];
  const int tx = threadIdx.x, ty = threadIdx.y;
  const int c0 = blockIdx.x * 32, r0 = blockIdx.y * 32;
  #pragma unroll
  for (int i = ty; i < 32; i += 8)
    tile[i][tx] = W[(long)(r0 + i) * cols + (c0 + tx)];
  __syncthreads();
  #pragma unroll
  for (int i = ty; i < 32; i += 8)
    Wt[(long)(c0 + i) * rows + (r0 + tx)] = f2bu(tile[tx][i]);
}

// ---------------- 256x256 8-phase GEMM: C[M][N] = A[M][K] @ Bt[N][K]^T --------
// 8 waves (2M x 4N), BK=64, LDS 128KB = 2 dbuf x {A[2ks][256][32], B[2ks][256][32]}
// Phase = (ksub, colhalf); 16 MFMA/phase; stage 1 K-half unit (2 gloads)/phase;
// vmcnt(4) once per K-tile. LDS swizzle: k-chunk ^= (row&3), both sides.
// EPI=1: C = bf16(relu(acc+bias[col]));  EPI=2: oacc[row] += sum relu(..)*w3
extern __shared__ char smem[];

template<int EPI>
__global__ __launch_bounds__(512, 2)
void k_gemm8(const u16* __restrict__ A, const u16* __restrict__ Bt,
             u16* __restrict__ C, const float* __restrict__ bias,
             const float* __restrict__ w3, float* __restrict__ oacc,
             int N, int K) {
  const int tid = threadIdx.x;
  const int w = tid >> 6, lane = tid & 63;
  // XCD-aware bijective swizzle (gridDim.x % 8 == 0 guaranteed: 2048 blocks)
  const int id = blockIdx.x;
  const int cpx = gridDim.x >> 3;
  const int sw = (id & 7) * cpx + (id >> 3);
  const int bn = sw & 7, bm = sw >> 3;          // N/256 == 8 for all our calls

  const int wm = (w >> 2) * 128, wn = (w & 3) * 64;
  const int nt = K >> 6;

  f4v acc[8][4];
  #pragma unroll
  for (int i = 0; i < 8; ++i)
    #pragma unroll
    for (int jj = 0; jj < 4; ++jj)
      #pragma unroll
      for (int r = 0; r < 4; ++r) acc[i][jj][r] = 0.f;

  // ---- staging bases (pre-swizzled global source, linear LDS dest) ----
  const int rowl = tid >> 2;                    // 0..127 row within chunk
  const int jsw = (tid & 3) ^ (rowl & 3);       // swizzled k-chunk
  const u16* gA = A + (long)(bm * 256 + rowl) * K + jsw * 8;
  const u16* gB = Bt + (long)(bn * 256 + rowl) * K + jsw * 8;
  const long cstr = (long)128 * K;              // chunk-1 global row offset
  const uint wb = (uint)w * 1024u;              // wave slice within 8KB chunk

  // ---- ds_read bases (swizzled) ----
  const uint swz = ((uint)((lane >> 4) ^ (lane & 3))) * 16u;
  const uint aoff = (uint)(wm + (lane & 15)) * 64u + swz;            // A region
  const uint boff = (uint)(wn + (lane & 15)) * 64u + swz + 32768u;   // B region

#define STAGE_A(pp, ks, t) do { \
    const u16* g_ = gA + (long)(t) * 64 + (ks) * 32; \
    char* l_ = smem + (uint)(pp) * 65536u + (uint)(ks) * 16384u + wb; \
    gload16(g_, l_); gload16(g_ + cstr, l_ + 8192); } while (0)
#define STAGE_B(pp, ks, t) do { \
    const u16* g_ = gB + (long)(t) * 64 + (ks) * 32; \
    char* l_ = smem + (uint)(pp) * 65536u + 32768u + (uint)(ks) * 16384u + wb; \
    gload16(g_, l_); gload16(g_ + cstr, l_ + 8192); } while (0)

#define MFMA8(c0i, c1i) do { \
    __builtin_amdgcn_s_setprio(1); \
    _Pragma("unroll") \
    for (int mi = 0; mi < 8; ++mi) { \
      acc[mi][c0i] = __builtin_amdgcn_mfma_f32_16x16x32_bf16(afr[mi], bfr[0], acc[mi][c0i], 0, 0, 0); \
      acc[mi][c1i] = __builtin_amdgcn_mfma_f32_16x16x32_bf16(afr[mi], bfr[1], acc[mi][c1i], 0, 0, 0); \
    } \
    __builtin_amdgcn_s_setprio(0); } while (0)

  // ---- prologue: tile0 complete + tile1 k0 units; drain tile0 (vmcnt 4) ----
  STAGE_A(0, 0, 0); STAGE_B(0, 0, 0); STAGE_A(0, 1, 0); STAGE_B(0, 1, 0);
  if (nt > 1) { STAGE_A(1, 0, 1); STAGE_B(1, 0, 1); VM(4); }
  else        { VM(0); }
  BAR();

  s8v afr[8], bfr[2];
  for (int t = 0; t < nt; ++t) {
    const int p = t & 1, q = p ^ 1;
    const uint pb = (uint)p * 65536u;
    // ---- P1: ksub0, colhalf0 ----
    #pragma unroll
    for (int mi = 0; mi < 8; ++mi)
      afr[mi] = *(const s8v*)(smem + pb + aoff + (uint)mi * 1024u);
    bfr[0] = *(const s8v*)(smem + pb + boff);
    bfr[1] = *(const s8v*)(smem + pb + boff + 1024u);
    if (t + 1 < nt) STAGE_A(q, 1, t + 1);     // -> q.A_k1 (q last read prev tile)
    BAR(); LGKM0();
    MFMA8(0, 1);
    BAR();
    // ---- P2: ksub0, colhalf1 (reuse afr) ----
    bfr[0] = *(const s8v*)(smem + pb + boff + 2048u);
    bfr[1] = *(const s8v*)(smem + pb + boff + 3072u);
    if (t + 1 < nt) STAGE_B(q, 1, t + 1);     // -> q.B_k1
    BAR(); LGKM0();
    MFMA8(2, 3);
    BAR();
    // ---- P3: ksub1, colhalf0 ----
    #pragma unroll
    for (int mi = 0; mi < 8; ++mi)
      afr[mi] = *(const s8v*)(smem + pb + 16384u + aoff + (uint)mi * 1024u);
    bfr[0] = *(const s8v*)(smem + pb + boff + 16384u);
    bfr[1] = *(const s8v*)(smem + pb + boff + 16384u + 1024u);
    if (t + 2 < nt) STAGE_A(p, 0, t + 2);     // -> p.A_k0 (last read at P1)
    BAR(); LGKM0();
    MFMA8(0, 1);
    BAR();
    // ---- P4: ksub1, colhalf1 ----
    bfr[0] = *(const s8v*)(smem + pb + boff + 16384u + 2048u);
    bfr[1] = *(const s8v*)(smem + pb + boff + 16384u + 3072u);
    if (t + 2 < nt) { STAGE_B(p, 0, t + 2); VM(4); }   // drain all of tile t+1
    else            { VM(0); }
    BAR(); LGKM0();
    MFMA8(2, 3);
    BAR();
  }

  // ---- epilogue (C/D: col = lane&15, row = (lane>>4)*4 + reg) ----
  const int crow = bm * 256 + wm + ((lane >> 4) << 2);
  const int ccol = bn * 256 + wn + (lane & 15);
  if (EPI == 1) {
    #pragma unroll
    for (int jj = 0; jj < 4; ++jj) {
      const float bb = bias[ccol + jj * 16];
      #pragma unroll
      for (int mi = 0; mi < 8; ++mi)
        #pragma unroll
        for (int r = 0; r < 4; ++r) {
          float v = acc[mi][jj][r] + bb;
          v = v > 0.f ? v : 0.f;
          C[(long)(crow + mi * 16 + r) * N + ccol + jj * 16] = f2bu(v);
        }
    }
  } else {
    float bb[4], ww[4];
    #pragma unroll
    for (int jj = 0; jj < 4; ++jj) { bb[jj] = bias[ccol + jj * 16]; ww[jj] = w3[ccol + jj * 16]; }
    #pragma unroll
    for (int mi = 0; mi < 8; ++mi)
      #pragma unroll
      for (int r = 0; r < 4; ++r) {
        float s = 0.f;
        #pragma unroll
        for (int jj = 0; jj < 4; ++jj) {
          float v = acc[mi][jj][r] + bb[jj];
          v = v > 0.f ? v : 0.f;
          s += v * ww[jj];
        }
        s += __shfl_xor(s, 1, 64);
        s += __shfl_xor(s, 2, 64);
        s += __shfl_xor(s, 4, 64);
        s += __shfl_xor(s, 8, 64);
        if ((lane & 15) == 0) atomicAdd(&oacc[crow + mi * 16 + r], s);
      }
  }
#undef STAGE_A
#undef STAGE_B
#undef MFMA8
}

// ---------------- segment ops ----------------
__global__ void k_detect(const int* __restrict__ seg, int n, int* __restrict__ flag) {
  if (blockIdx.x == 0 && threadIdx.x == 0) flag[0] = (seg[n - 1] == 0) ? 1 : 0;
}

__global__ void k_segsum(const float* __restrict__ oacc, const float* __restrict__ wacc,
                         const int* __restrict__ seg, const int* __restrict__ flag,
                         const float* __restrict__ ob3, const float* __restrict__ wb3,
                         float* __restrict__ osum, float* __restrict__ wsum, int n) {
  int i = blockIdx.x * blockDim.x + threadIdx.x;
  if (i >= n) return;
  int s = flag[0] ? seg[2 * i] : seg[i];
  atomicAdd(&osum[s], oacc[i] + ob3[0]);
  atomicAdd(&wsum[s], wacc[i] + wb3[0]);
}

__global__ void k_final(const float* __restrict__ oacc, const float* __restrict__ wacc,
                        const int* __restrict__ seg, const int* __restrict__ flag,
                        const float* __restrict__ ob3, const float* __restrict__ wb3,
                        const float* __restrict__ osum, const float* __restrict__ wsum,
                        float* __restrict__ out, int n) {
  int i = blockIdx.x * blockDim.x + threadIdx.x;
  if (i >= n) return;
  int s = flag[0] ? seg[2 * i] : seg[i];
  float o = oacc[i] + ob3[0];
  float ww = wacc[i] + wb3[0];
  out[i] = o - ww * (osum[s] / wsum[s]);
}

extern "C" void kernel_launch(void* const* d_in, const int* in_sizes, int n_in,
                              void* d_out, int out_size, void* d_ws, size_t ws_size,
                              hipStream_t stream) {
  constexpr int NA = 65536, D = 1024, H = 2048, M = 4096;
  const float* hidden = (const float*)d_in[0];
  const float* fW1 = (const float*)d_in[1];
  const float* fb1 = (const float*)d_in[2];
  const float* fW2 = (const float*)d_in[3];
  const float* fb2 = (const float*)d_in[4];
  const float* fW3 = (const float*)d_in[5];
  const float* fb3 = (const float*)d_in[6];
  const float* wW1 = (const float*)d_in[7];
  const float* wb1 = (const float*)d_in[8];
  const float* wW2 = (const float*)d_in[9];
  const float* wb2 = (const float*)d_in[10];
  const float* wW3 = (const float*)d_in[11];
  const float* wb3 = (const float*)d_in[12];
  const int* seg = (const int*)d_in[13];
  float* out = (float*)d_out;

  char* ws = (char*)d_ws;
  size_t off = 0;
  auto alloc = [&](size_t bytes) { char* p = ws + off; off += (bytes + 255) & ~(size_t)255; return p; };
  u16* hbf  = (u16*)alloc((size_t)NA * D * 2);
  u16* w1tf = (u16*)alloc((size_t)H * D * 2);
  u16* w1tw = (u16*)alloc((size_t)H * D * 2);
  u16* w2tf = (u16*)alloc((size_t)H * H * 2);
  u16* w2tw = (u16*)alloc((size_t)H * H * 2);
  u16* h1   = (u16*)alloc((size_t)NA * H * 2);
  float* oacc = (float*)alloc((size_t)NA * 4);
  float* wacc = (float*)alloc((size_t)NA * 4);
  float* osum = (float*)alloc((size_t)M * 4);
  float* wsum = (float*)alloc((size_t)M * 4);
  int* flag = (int*)alloc(256);

  // allow 128KB dynamic LDS (host-side attribute; capture-legal)
  hipFuncSetAttribute((const void*)k_gemm8<1>, hipFuncAttributeMaxDynamicSharedMemorySize, 131072);
  hipFuncSetAttribute((const void*)k_gemm8<2>, hipFuncAttributeMaxDynamicSharedMemorySize, 131072);

  // conversions
  k_f32_to_bf16<<<(int)((long)NA * D / 4 / 256), 256, 0, stream>>>(hidden, hbf, (long)NA * D / 4);
  dim3 tb(32, 8);
  k_transpose_bf16<<<dim3(H / 32, D / 32), tb, 0, stream>>>(fW1, w1tf, D, H);
  k_transpose_bf16<<<dim3(H / 32, D / 32), tb, 0, stream>>>(wW1, w1tw, D, H);
  k_transpose_bf16<<<dim3(H / 32, H / 32), tb, 0, stream>>>(fW2, w2tf, H, H);
  k_transpose_bf16<<<dim3(H / 32, H / 32), tb, 0, stream>>>(wW2, w2tw, H, H);

  hipMemsetAsync(oacc, 0, (size_t)((char*)flag - (char*)oacc), stream);
  k_detect<<<1, 64, 0, stream>>>(seg, NA, flag);

  const int nblk = (H / 256) * (NA / 256);   // 8 * 256 = 2048
  // ffn branch
  k_gemm8<1><<<nblk, 512, 131072, stream>>>(hbf, w1tf, h1, fb1, nullptr, nullptr, H, D);
  k_gemm8<2><<<nblk, 512, 131072, stream>>>(h1, w2tf, nullptr, fb2, fW3, oacc, H, H);
  // weight branch (reuses h1)
  k_gemm8<1><<<nblk, 512, 131072, stream>>>(hbf, w1tw, h1, wb1, nullptr, nullptr, H, D);
  k_gemm8<2><<<nblk, 512, 131072, stream>>>(h1, w2tw, nullptr, wb2, wW3, wacc, H, H);

  // segment ratio + final
  k_segsum<<<NA / 256, 256, 0, stream>>>(oacc, wacc, seg, flag, fb3, wb3, osum, wsum, NA);
  k_final<<<NA / 256, 256, 0, stream>>>(oacc, wacc, seg, flag, fb3, wb3, osum, wsum, out, NA);
}

// Round 3
// 1958.470 us; speedup vs baseline: 1.0899x; 1.0421x over previous
//
#include <hip/hip_runtime.h>
#include <hip/hip_bf16.h>

#define DEVINL __device__ __forceinline__

typedef __attribute__((ext_vector_type(8))) short s8v;   // 8 x bf16 bits
typedef __attribute__((ext_vector_type(4))) float f4v;   // MFMA accum

using bf16 = __hip_bfloat16;
typedef unsigned short u16;

DEVINL u16 f2bu(float f) {
  bf16 h = __float2bfloat16(f);  // RNE
  return *reinterpret_cast<u16*>(&h);
}

DEVINL void gload16(const void* g, void* l) {
  // async global->LDS, 16B/lane; LDS dest = wave-uniform base + lane*16
  __builtin_amdgcn_global_load_lds((const __attribute__((address_space(1))) void*)g,
                                   (__attribute__((address_space(3))) void*)l, 16, 0, 0);
}

#define BAR()   __builtin_amdgcn_s_barrier()
#define LGKM0() asm volatile("s_waitcnt lgkmcnt(0)" ::: "memory")
#define VM(n)   asm volatile("s_waitcnt vmcnt(" #n ")" ::: "memory")

// ---------------- conversion kernels ----------------
__global__ void k_f32_to_bf16(const float* __restrict__ x, u16* __restrict__ y, long n4) {
  long i = (long)blockIdx.x * blockDim.x + threadIdx.x;
  if (i >= n4) return;
  float4 v = ((const float4*)x)[i];
  ushort4 o;
  o.x = f2bu(v.x); o.y = f2bu(v.y); o.z = f2bu(v.z); o.w = f2bu(v.w);
  ((ushort4*)y)[i] = o;
}

// W [rows][cols] fp32 -> Wt [cols][rows] bf16
__global__ void k_transpose_bf16(const float* __restrict__ W, u16* __restrict__ Wt,
                                 int rows, int cols) {
  __shared__ float tile[32][33];
  const int tx = threadIdx.x, ty = threadIdx.y;
  const int c0 = blockIdx.x * 32, r0 = blockIdx.y * 32;
  #pragma unroll
  for (int i = ty; i < 32; i += 8)
    tile[i][tx] = W[(long)(r0 + i) * cols + (c0 + tx)];
  __syncthreads();
  #pragma unroll
  for (int i = ty; i < 32; i += 8)
    Wt[(long)(c0 + i) * rows + (r0 + tx)] = f2bu(tile[tx][i]);
}

// ---------------- 256x256 8-phase GEMM: C[M][N] = A[M][K] @ Bt[N][K]^T --------
// 8 waves (2M x 4N), BK=64, LDS 128KB = 2 dbuf x {A[2ks][256][32], B[2ks][256][32]}
// Swizzle: 16B slot j of row r holds k-chunk j ^ ((r>>1)&3)  -> conflict-free
// ds_read_b128 (8-lane batches hit 8 distinct 16B slots mod 128B).
// vmcnt(8) at P2 (drain this tile k1) and P4 (drain next tile k0); VM(0) tail.
// EPI=1: C = bf16(relu(acc+bias[col]));  EPI=2: oacc[row] += sum relu(..)*w3
extern __shared__ char smem[];

template<int EPI>
__global__ __launch_bounds__(512, 2)
void k_gemm8(const u16* __restrict__ A, const u16* __restrict__ Bt,
             u16* __restrict__ C, const float* __restrict__ bias,
             const float* __restrict__ w3, float* __restrict__ oacc,
             int N, int K) {
  const int tid = threadIdx.x;
  const int w = tid >> 6, lane = tid & 63;
  // XCD-aware bijective swizzle (gridDim.x % 8 == 0: 2048 blocks)
  const int id = blockIdx.x;
  const int cpx = gridDim.x >> 3;
  const int sw = (id & 7) * cpx + (id >> 3);
  const int bn = sw & 7, bm = sw >> 3;          // N/256 == 8 for all our calls

  const int wm = (w >> 2) * 128, wn = (w & 3) * 64;
  const int nt = K >> 6;

  f4v acc[8][4];
  #pragma unroll
  for (int i = 0; i < 8; ++i)
    #pragma unroll
    for (int jj = 0; jj < 4; ++jj)
      #pragma unroll
      for (int r = 0; r < 4; ++r) acc[i][jj][r] = 0.f;

  // ---- staging bases (pre-swizzled global source, linear LDS dest) ----
  const int rowl = tid >> 2;                           // 0..127 row within chunk
  const int jsw = (tid & 3) ^ ((rowl >> 1) & 3);       // swizzled k-chunk
  const u16* gA = A + (long)(bm * 256 + rowl) * K + jsw * 8;
  const u16* gB = Bt + (long)(bn * 256 + rowl) * K + jsw * 8;
  const long cstr = (long)128 * K;                     // chunk-1 global row offset
  const uint wb = (uint)w * 1024u;                     // wave slice within 8KB chunk

  // ---- ds_read bases (swizzled; (row>>1)&3 == (lane>>1)&3 for all our rows) ----
  const uint swz = ((uint)((lane >> 4) ^ ((lane >> 1) & 3))) * 16u;
  const uint aoff = (uint)(wm + (lane & 15)) * 64u + swz;            // A region
  const uint boff = (uint)(wn + (lane & 15)) * 64u + swz + 32768u;   // B region

#define STAGE_A(pp, ks, t) do { \
    const u16* g_ = gA + (long)(t) * 64 + (ks) * 32; \
    char* l_ = smem + (uint)(pp) * 65536u + (uint)(ks) * 16384u + wb; \
    gload16(g_, l_); gload16(g_ + cstr, l_ + 8192); } while (0)
#define STAGE_B(pp, ks, t) do { \
    const u16* g_ = gB + (long)(t) * 64 + (ks) * 32; \
    char* l_ = smem + (uint)(pp) * 65536u + 32768u + (uint)(ks) * 16384u + wb; \
    gload16(g_, l_); gload16(g_ + 8192 * 0 + cstr, l_ + 8192); } while (0)

#define MFMA8(c0i, c1i) do { \
    __builtin_amdgcn_s_setprio(1); \
    _Pragma("unroll") \
    for (int mi = 0; mi < 8; ++mi) { \
      acc[mi][c0i] = __builtin_amdgcn_mfma_f32_16x16x32_bf16(afr[mi], bfr[0], acc[mi][c0i], 0, 0, 0); \
      acc[mi][c1i] = __builtin_amdgcn_mfma_f32_16x16x32_bf16(afr[mi], bfr[1], acc[mi][c1i], 0, 0, 0); \
    } \
    __builtin_amdgcn_s_setprio(0); } while (0)

  // ---- prologue: tile0 complete + tile1 k0 units; drain tile0 (vmcnt 4) ----
  STAGE_A(0, 0, 0); STAGE_B(0, 0, 0); STAGE_A(0, 1, 0); STAGE_B(0, 1, 0);
  if (nt > 1) { STAGE_A(1, 0, 1); STAGE_B(1, 0, 1); VM(4); }
  else        { VM(0); }
  BAR();

  s8v afr[8], bfr[2];
  for (int t = 0; t < nt; ++t) {
    const int p = t & 1, q = p ^ 1;
    const uint pb = (uint)p * 65536u;
    // ---- P1: ksub0, colhalf0 ----
    #pragma unroll
    for (int mi = 0; mi < 8; ++mi)
      afr[mi] = *(const s8v*)(smem + pb + aoff + (uint)mi * 1024u);
    bfr[0] = *(const s8v*)(smem + pb + boff);
    bfr[1] = *(const s8v*)(smem + pb + boff + 1024u);
    if (t + 1 < nt) STAGE_A(q, 1, t + 1);     // -> q.A_k1
    BAR(); LGKM0();
    MFMA8(0, 1);
    BAR();
    // ---- P2: ksub0, colhalf1 (reuse afr) ----
    bfr[0] = *(const s8v*)(smem + pb + boff + 2048u);
    bfr[1] = *(const s8v*)(smem + pb + boff + 3072u);
    if (t + 1 < nt) STAGE_B(q, 1, t + 1);     // -> q.B_k1
    VM(8);                                    // drain this tile's k1 (for P3)
    BAR(); LGKM0();
    MFMA8(2, 3);
    BAR();
    // ---- P3: ksub1, colhalf0 ----
    #pragma unroll
    for (int mi = 0; mi < 8; ++mi)
      afr[mi] = *(const s8v*)(smem + pb + 16384u + aoff + (uint)mi * 1024u);
    bfr[0] = *(const s8v*)(smem + pb + boff + 16384u);
    bfr[1] = *(const s8v*)(smem + pb + boff + 16384u + 1024u);
    if (t + 2 < nt) STAGE_A(p, 0, t + 2);     // -> p.A_k0 (last read at P1)
    BAR(); LGKM0();
    MFMA8(0, 1);
    BAR();
    // ---- P4: ksub1, colhalf1 ----
    bfr[0] = *(const s8v*)(smem + pb + boff + 16384u + 2048u);
    bfr[1] = *(const s8v*)(smem + pb + boff + 16384u + 3072u);
    if (t + 2 < nt) { STAGE_B(p, 0, t + 2); VM(8); }  // drain next tile's k0
    else            { VM(0); }                        // tail: drain everything
    BAR(); LGKM0();
    MFMA8(2, 3);
    BAR();
  }

  // ---- epilogue (C/D: col = lane&15, row = (lane>>4)*4 + reg) ----
  const int crow = bm * 256 + wm + ((lane >> 4) << 2);
  const int ccol = bn * 256 + wn + (lane & 15);
  if (EPI == 1) {
    #pragma unroll
    for (int jj = 0; jj < 4; ++jj) {
      const float bb = bias[ccol + jj * 16];
      #pragma unroll
      for (int mi = 0; mi < 8; ++mi)
        #pragma unroll
        for (int r = 0; r < 4; ++r) {
          float v = acc[mi][jj][r] + bb;
          v = v > 0.f ? v : 0.f;
          C[(long)(crow + mi * 16 + r) * N + ccol + jj * 16] = f2bu(v);
        }
    }
  } else {
    float bb[4], ww[4];
    #pragma unroll
    for (int jj = 0; jj < 4; ++jj) { bb[jj] = bias[ccol + jj * 16]; ww[jj] = w3[ccol + jj * 16]; }
    #pragma unroll
    for (int mi = 0; mi < 8; ++mi)
      #pragma unroll
      for (int r = 0; r < 4; ++r) {
        float s = 0.f;
        #pragma unroll
        for (int jj = 0; jj < 4; ++jj) {
          float v = acc[mi][jj][r] + bb[jj];
          v = v > 0.f ? v : 0.f;
          s += v * ww[jj];
        }
        s += __shfl_xor(s, 1, 64);
        s += __shfl_xor(s, 2, 64);
        s += __shfl_xor(s, 4, 64);
        s += __shfl_xor(s, 8, 64);
        if ((lane & 15) == 0) atomicAdd(&oacc[crow + mi * 16 + r], s);
      }
  }
#undef STAGE_A
#undef STAGE_B
#undef MFMA8
}

// ---------------- segment ops ----------------
__global__ void k_detect(const int* __restrict__ seg, int n, int* __restrict__ flag) {
  if (blockIdx.x == 0 && threadIdx.x == 0) flag[0] = (seg[n - 1] == 0) ? 1 : 0;
}

__global__ void k_segsum(const float* __restrict__ oacc, const float* __restrict__ wacc,
                         const int* __restrict__ seg, const int* __restrict__ flag,
                         const float* __restrict__ ob3, const float* __restrict__ wb3,
                         float* __restrict__ osum, float* __restrict__ wsum, int n) {
  int i = blockIdx.x * blockDim.x + threadIdx.x;
  if (i >= n) return;
  int s = flag[0] ? seg[2 * i] : seg[i];
  atomicAdd(&osum[s], oacc[i] + ob3[0]);
  atomicAdd(&wsum[s], wacc[i] + wb3[0]);
}

__global__ void k_final(const float* __restrict__ oacc, const float* __restrict__ wacc,
                        const int* __restrict__ seg, const int* __restrict__ flag,
                        const float* __restrict__ ob3, const float* __restrict__ wb3,
                        const float* __restrict__ osum, const float* __restrict__ wsum,
                        float* __restrict__ out, int n) {
  int i = blockIdx.x * blockDim.x + threadIdx.x;
  if (i >= n) return;
  int s = flag[0] ? seg[2 * i] : seg[i];
  float o = oacc[i] + ob3[0];
  float ww = wacc[i] + wb3[0];
  out[i] = o - ww * (osum[s] / wsum[s]);
}

extern "C" void kernel_launch(void* const* d_in, const int* in_sizes, int n_in,
                              void* d_out, int out_size, void* d_ws, size_t ws_size,
                              hipStream_t stream) {
  constexpr int NA = 65536, D = 1024, H = 2048, M = 4096;
  const float* hidden = (const float*)d_in[0];
  const float* fW1 = (const float*)d_in[1];
  const float* fb1 = (const float*)d_in[2];
  const float* fW2 = (const float*)d_in[3];
  const float* fb2 = (const float*)d_in[4];
  const float* fW3 = (const float*)d_in[5];
  const float* fb3 = (const float*)d_in[6];
  const float* wW1 = (const float*)d_in[7];
  const float* wb1 = (const float*)d_in[8];
  const float* wW2 = (const float*)d_in[9];
  const float* wb2 = (const float*)d_in[10];
  const float* wW3 = (const float*)d_in[11];
  const float* wb3 = (const float*)d_in[12];
  const int* seg = (const int*)d_in[13];
  float* out = (float*)d_out;

  char* ws = (char*)d_ws;
  size_t off = 0;
  auto alloc = [&](size_t bytes) { char* p = ws + off; off += (bytes + 255) & ~(size_t)255; return p; };
  u16* hbf  = (u16*)alloc((size_t)NA * D * 2);
  u16* w1tf = (u16*)alloc((size_t)H * D * 2);
  u16* w1tw = (u16*)alloc((size_t)H * D * 2);
  u16* w2tf = (u16*)alloc((size_t)H * H * 2);
  u16* w2tw = (u16*)alloc((size_t)H * H * 2);
  u16* h1   = (u16*)alloc((size_t)NA * H * 2);
  float* oacc = (float*)alloc((size_t)NA * 4);
  float* wacc = (float*)alloc((size_t)NA * 4);
  float* osum = (float*)alloc((size_t)M * 4);
  float* wsum = (float*)alloc((size_t)M * 4);
  int* flag = (int*)alloc(256);

  // allow 128KB dynamic LDS (host-side attribute; capture-legal)
  hipFuncSetAttribute((const void*)k_gemm8<1>, hipFuncAttributeMaxDynamicSharedMemorySize, 131072);
  hipFuncSetAttribute((const void*)k_gemm8<2>, hipFuncAttributeMaxDynamicSharedMemorySize, 131072);

  // conversions
  k_f32_to_bf16<<<(int)((long)NA * D / 4 / 256), 256, 0, stream>>>(hidden, hbf, (long)NA * D / 4);
  dim3 tb(32, 8);
  k_transpose_bf16<<<dim3(H / 32, D / 32), tb, 0, stream>>>(fW1, w1tf, D, H);
  k_transpose_bf16<<<dim3(H / 32, D / 32), tb, 0, stream>>>(wW1, w1tw, D, H);
  k_transpose_bf16<<<dim3(H / 32, H / 32), tb, 0, stream>>>(fW2, w2tf, H, H);
  k_transpose_bf16<<<dim3(H / 32, H / 32), tb, 0, stream>>>(wW2, w2tw, H, H);

  hipMemsetAsync(oacc, 0, (size_t)((char*)flag - (char*)oacc), stream);
  k_detect<<<1, 64, 0, stream>>>(seg, NA, flag);

  const int nblk = (H / 256) * (NA / 256);   // 8 * 256 = 2048
  // ffn branch
  k_gemm8<1><<<nblk, 512, 131072, stream>>>(hbf, w1tf, h1, fb1, nullptr, nullptr, H, D);
  k_gemm8<2><<<nblk, 512, 131072, stream>>>(h1, w2tf, nullptr, fb2, fW3, oacc, H, H);
  // weight branch (reuses h1)
  k_gemm8<1><<<nblk, 512, 131072, stream>>>(hbf, w1tw, h1, wb1, nullptr, nullptr, H, D);
  k_gemm8<2><<<nblk, 512, 131072, stream>>>(h1, w2tw, nullptr, wb2, wW3, wacc, H, H);

  // segment ratio + final
  k_segsum<<<NA / 256, 256, 0, stream>>>(oacc, wacc, seg, flag, fb3, wb3, osum, wsum, NA);
  k_final<<<NA / 256, 256, 0, stream>>>(oacc, wacc, seg, flag, fb3, wb3, osum, wsum, out, NA);
}

// Round 4
// 1935.825 us; speedup vs baseline: 1.1027x; 1.0117x over previous
//
#include <hip/hip_runtime.h>
#include <hip/hip_bf16.h>

#define DEVINL __device__ __forceinline__

typedef __attribute__((ext_vector_type(8))) short s8v;   // 8 x bf16 bits
typedef __attribute__((ext_vector_type(4))) float f4v;   // MFMA accum

using bf16 = __hip_bfloat16;
typedef unsigned short u16;

DEVINL u16 f2bu(float f) {
  bf16 h = __float2bfloat16(f);  // RNE
  return *reinterpret_cast<u16*>(&h);
}

DEVINL void gload16(const void* g, void* l) {
  // async global->LDS, 16B/lane; LDS dest = wave-uniform base + lane*16
  __builtin_amdgcn_global_load_lds((const __attribute__((address_space(1))) void*)g,
                                   (__attribute__((address_space(3))) void*)l, 16, 0, 0);
}

#define BAR()    __builtin_amdgcn_s_barrier()
#define LGKM(n)  asm volatile("s_waitcnt lgkmcnt(" #n ")" ::: "memory")
#define VM(n)    asm volatile("s_waitcnt vmcnt(" #n ")" ::: "memory")

// ---------------- conversion kernels ----------------
__global__ void k_f32_to_bf16(const float* __restrict__ x, u16* __restrict__ y, long n4) {
  long i = (long)blockIdx.x * blockDim.x + threadIdx.x;
  if (i >= n4) return;
  float4 v = ((const float4*)x)[i];
  ushort4 o;
  o.x = f2bu(v.x); o.y = f2bu(v.y); o.z = f2bu(v.z); o.w = f2bu(v.w);
  ((ushort4*)y)[i] = o;
}

// W [rows][cols] fp32 -> Wt [cols][rows] bf16
__global__ void k_transpose_bf16(const float* __restrict__ W, u16* __restrict__ Wt,
                                 int rows, int cols) {
  __shared__ float tile[32][33];
  const int tx = threadIdx.x, ty = threadIdx.y;
  const int c0 = blockIdx.x * 32, r0 = blockIdx.y * 32;
  #pragma unroll
  for (int i = ty; i < 32; i += 8)
    tile[i][tx] = W[(long)(r0 + i) * cols + (c0 + tx)];
  __syncthreads();
  #pragma unroll
  for (int i = ty; i < 32; i += 8)
    Wt[(long)(c0 + i) * rows + (r0 + tx)] = f2bu(tile[tx][i]);
}

// ---------------- 256x256 8-phase GEMM, fragment-pipelined --------------------
// 8 waves (2M x 4N), BK=64, LDS 128KB = 2 dbuf x {A[2ks][256][32], B[2ks][256][32]}
// Swizzle: 16B slot j of row r holds k-chunk j ^ ((r>>1)&3) (conflict-free b128).
// Frag pipeline: reads for phase N+1 issued before MFMA(N); counted lgkm gates.
// Drains: VM(6)@P2 (this tile k1), VM(8)@P4 (next tile k0); 4 barriers/K-tile.
// EPI=1: C = bf16(relu(acc+bias[col]));  EPI=2: oacc[row] += sum relu(..)*w3
extern __shared__ char smem[];

template<int EPI>
__global__ __launch_bounds__(512, 2)
void k_gemm8(const u16* __restrict__ A, const u16* __restrict__ Bt,
             u16* __restrict__ C, const float* __restrict__ bias,
             const float* __restrict__ w3, float* __restrict__ oacc,
             int N, int K) {
  const int tid = threadIdx.x;
  const int w = tid >> 6, lane = tid & 63;
  // XCD-aware bijective swizzle (gridDim.x % 8 == 0: 2048 blocks)
  const int id = blockIdx.x;
  const int cpx = gridDim.x >> 3;
  const int sw = (id & 7) * cpx + (id >> 3);
  const int bn = sw & 7, bm = sw >> 3;          // N/256 == 8 for all our calls

  const int wm = (w >> 2) * 128, wn = (w & 3) * 64;
  const int nt = K >> 6;

  f4v acc[8][4];
  #pragma unroll
  for (int i = 0; i < 8; ++i)
    #pragma unroll
    for (int jj = 0; jj < 4; ++jj)
      #pragma unroll
      for (int r = 0; r < 4; ++r) acc[i][jj][r] = 0.f;

  // ---- staging bases (pre-swizzled global source, linear LDS dest) ----
  const int rowl = tid >> 2;                           // 0..127 row within chunk
  const int jsw = (tid & 3) ^ ((rowl >> 1) & 3);       // swizzled k-chunk
  const u16* gA = A + (long)(bm * 256 + rowl) * K + jsw * 8;
  const u16* gB = Bt + (long)(bn * 256 + rowl) * K + jsw * 8;
  const long cstr = (long)128 * K;                     // chunk-1 global row offset
  const uint wb = (uint)w * 1024u;                     // wave slice within 8KB chunk

  // ---- ds_read bases (swizzled) ----
  const uint swz = ((uint)((lane >> 4) ^ ((lane >> 1) & 3))) * 16u;
  const uint aoff = (uint)(wm + (lane & 15)) * 64u + swz;            // A region
  const uint boff = (uint)(wn + (lane & 15)) * 64u + swz + 32768u;   // B region

#define STAGE_A(pp, ks, t) do { \
    const u16* g_ = gA + (long)(t) * 64 + (ks) * 32; \
    char* l_ = smem + (uint)(pp) * 65536u + (uint)(ks) * 16384u + wb; \
    gload16(g_, l_); gload16(g_ + cstr, l_ + 8192); } while (0)
#define STAGE_B(pp, ks, t) do { \
    const u16* g_ = gB + (long)(t) * 64 + (ks) * 32; \
    char* l_ = smem + (uint)(pp) * 65536u + 32768u + (uint)(ks) * 16384u + wb; \
    gload16(g_, l_); gload16(g_ + cstr, l_ + 8192); } while (0)

#define RD_A(dst, base, ksb) do { \
    _Pragma("unroll") \
    for (int mi_ = 0; mi_ < 8; ++mi_) \
      dst[mi_] = *(const s8v*)(smem + (base) + (ksb) + aoff + (uint)mi_ * 1024u); } while (0)
#define RD_B(dst, base, ksb, c0) do { \
    dst[0] = *(const s8v*)(smem + (base) + (ksb) + boff + (uint)(c0) * 1024u); \
    dst[1] = *(const s8v*)(smem + (base) + (ksb) + boff + (uint)((c0) + 1) * 1024u); } while (0)

#define MFMA8(A_, B_, c0i, c1i) do { \
    __builtin_amdgcn_s_setprio(1); \
    _Pragma("unroll") \
    for (int mi_ = 0; mi_ < 8; ++mi_) { \
      acc[mi_][c0i] = __builtin_amdgcn_mfma_f32_16x16x32_bf16(A_[mi_], B_[0], acc[mi_][c0i], 0, 0, 0); \
      acc[mi_][c1i] = __builtin_amdgcn_mfma_f32_16x16x32_bf16(A_[mi_], B_[1], acc[mi_][c1i], 0, 0, 0); \
    } \
    __builtin_amdgcn_s_setprio(0); } while (0)

  s8v a0[8], a1[8], b01[2], b23[2];

  // ---- prologue: stage t0 fully + t1.k0; drain t0.k0; issue t0 P1 reads ----
  STAGE_A(0, 0, 0); STAGE_B(0, 0, 0); STAGE_A(0, 1, 0); STAGE_B(0, 1, 0);
  if (nt > 1) { STAGE_A(1, 0, 1); STAGE_B(1, 0, 1); VM(8); }
  else        { VM(4); }
  BAR();
  RD_A(a0, 0u, 0u); RD_B(b01, 0u, 0u, 0);   // 10 reads in flight for P1

  for (int t = 0; t < nt; ++t) {
    const int p = t & 1, q = p ^ 1;
    const uint pb = (uint)p * 65536u, qb = (uint)q * 65536u;
    // ---- P1: MFMA(k0, cols 0-1); prefetch b23(k0) ----
    RD_B(b23, pb, 0u, 2);
    if (t + 1 < nt) STAGE_A(q, 1, t + 1);      // (t+1).Ak1
    BAR(); LGKM(2);
    MFMA8(a0, b01, 0, 1);
    // ---- P2: MFMA(k0, cols 2-3); prefetch k1 frags ----
    if (t + 1 < nt) { VM(6); } else { VM(0); } // tile t k1 landed
    BAR();
    RD_A(a1, pb, 16384u); RD_B(b01, pb, 16384u, 0);
    if (t + 1 < nt) STAGE_B(q, 1, t + 1);      // (t+1).Bk1
    LGKM(10);
    MFMA8(a0, b23, 2, 3);
    // ---- P3: MFMA(k1, cols 0-1); prefetch b23(k1) ----
    RD_B(b23, pb, 16384u, 2);
    if (t + 2 < nt) STAGE_A(p, 0, t + 2);      // (t+2).Ak0
    BAR(); LGKM(2);
    MFMA8(a1, b01, 0, 1);
    // ---- P4: MFMA(k1, cols 2-3); prefetch next tile k0 frags ----
    if (t + 2 < nt) {
      STAGE_B(p, 0, t + 2);                    // (t+2).Bk0
      VM(8); BAR();                            // (t+1).k0 landed
      RD_A(a0, qb, 0u); RD_B(b01, qb, 0u, 0);
      LGKM(10);
    } else if (t + 1 < nt) {
      VM(4); BAR();
      RD_A(a0, qb, 0u); RD_B(b01, qb, 0u, 0);
      LGKM(10);
    } else {
      BAR(); LGKM(0);
    }
    MFMA8(a1, b23, 2, 3);
  }

  // ---- epilogue (C/D: col = lane&15, row = (lane>>4)*4 + reg) ----
  const int crow = bm * 256 + wm + ((lane >> 4) << 2);
  const int ccol = bn * 256 + wn + (lane & 15);
  if (EPI == 1) {
    #pragma unroll
    for (int jj = 0; jj < 4; ++jj) {
      const float bb = bias[ccol + jj * 16];
      #pragma unroll
      for (int mi = 0; mi < 8; ++mi)
        #pragma unroll
        for (int r = 0; r < 4; ++r) {
          float v = acc[mi][jj][r] + bb;
          v = v > 0.f ? v : 0.f;
          C[(long)(crow + mi * 16 + r) * N + ccol + jj * 16] = f2bu(v);
        }
    }
  } else {
    float bb[4], ww[4];
    #pragma unroll
    for (int jj = 0; jj < 4; ++jj) { bb[jj] = bias[ccol + jj * 16]; ww[jj] = w3[ccol + jj * 16]; }
    #pragma unroll
    for (int mi = 0; mi < 8; ++mi)
      #pragma unroll
      for (int r = 0; r < 4; ++r) {
        float s = 0.f;
        #pragma unroll
        for (int jj = 0; jj < 4; ++jj) {
          float v = acc[mi][jj][r] + bb[jj];
          v = v > 0.f ? v : 0.f;
          s += v * ww[jj];
        }
        s += __shfl_xor(s, 1, 64);
        s += __shfl_xor(s, 2, 64);
        s += __shfl_xor(s, 4, 64);
        s += __shfl_xor(s, 8, 64);
        if ((lane & 15) == 0) atomicAdd(&oacc[crow + mi * 16 + r], s);
      }
  }
#undef STAGE_A
#undef STAGE_B
#undef RD_A
#undef RD_B
#undef MFMA8
}

// ---------------- segment ops ----------------
__global__ void k_detect(const int* __restrict__ seg, int n, int* __restrict__ flag) {
  if (blockIdx.x == 0 && threadIdx.x == 0) flag[0] = (seg[n - 1] == 0) ? 1 : 0;
}

__global__ void k_segsum(const float* __restrict__ oacc, const float* __restrict__ wacc,
                         const int* __restrict__ seg, const int* __restrict__ flag,
                         const float* __restrict__ ob3, const float* __restrict__ wb3,
                         float* __restrict__ osum, float* __restrict__ wsum, int n) {
  int i = blockIdx.x * blockDim.x + threadIdx.x;
  if (i >= n) return;
  int s = flag[0] ? seg[2 * i] : seg[i];
  atomicAdd(&osum[s], oacc[i] + ob3[0]);
  atomicAdd(&wsum[s], wacc[i] + wb3[0]);
}

__global__ void k_final(const float* __restrict__ oacc, const float* __restrict__ wacc,
                        const int* __restrict__ seg, const int* __restrict__ flag,
                        const float* __restrict__ ob3, const float* __restrict__ wb3,
                        const float* __restrict__ osum, const float* __restrict__ wsum,
                        float* __restrict__ out, int n) {
  int i = blockIdx.x * blockDim.x + threadIdx.x;
  if (i >= n) return;
  int s = flag[0] ? seg[2 * i] : seg[i];
  float o = oacc[i] + ob3[0];
  float ww = wacc[i] + wb3[0];
  out[i] = o - ww * (osum[s] / wsum[s]);
}

extern "C" void kernel_launch(void* const* d_in, const int* in_sizes, int n_in,
                              void* d_out, int out_size, void* d_ws, size_t ws_size,
                              hipStream_t stream) {
  constexpr int NA = 65536, D = 1024, H = 2048, M = 4096;
  const float* hidden = (const float*)d_in[0];
  const float* fW1 = (const float*)d_in[1];
  const float* fb1 = (const float*)d_in[2];
  const float* fW2 = (const float*)d_in[3];
  const float* fb2 = (const float*)d_in[4];
  const float* fW3 = (const float*)d_in[5];
  const float* fb3 = (const float*)d_in[6];
  const float* wW1 = (const float*)d_in[7];
  const float* wb1 = (const float*)d_in[8];
  const float* wW2 = (const float*)d_in[9];
  const float* wb2 = (const float*)d_in[10];
  const float* wW3 = (const float*)d_in[11];
  const float* wb3 = (const float*)d_in[12];
  const int* seg = (const int*)d_in[13];
  float* out = (float*)d_out;

  char* ws = (char*)d_ws;
  size_t off = 0;
  auto alloc = [&](size_t bytes) { char* p = ws + off; off += (bytes + 255) & ~(size_t)255; return p; };
  u16* hbf  = (u16*)alloc((size_t)NA * D * 2);
  u16* w1tf = (u16*)alloc((size_t)H * D * 2);
  u16* w1tw = (u16*)alloc((size_t)H * D * 2);
  u16* w2tf = (u16*)alloc((size_t)H * H * 2);
  u16* w2tw = (u16*)alloc((size_t)H * H * 2);
  u16* h1   = (u16*)alloc((size_t)NA * H * 2);
  float* oacc = (float*)alloc((size_t)NA * 4);
  float* wacc = (float*)alloc((size_t)NA * 4);
  float* osum = (float*)alloc((size_t)M * 4);
  float* wsum = (float*)alloc((size_t)M * 4);
  int* flag = (int*)alloc(256);

  // allow 128KB dynamic LDS (host-side attribute; capture-legal)
  hipFuncSetAttribute((const void*)k_gemm8<1>, hipFuncAttributeMaxDynamicSharedMemorySize, 131072);
  hipFuncSetAttribute((const void*)k_gemm8<2>, hipFuncAttributeMaxDynamicSharedMemorySize, 131072);

  // conversions
  k_f32_to_bf16<<<(int)((long)NA * D / 4 / 256), 256, 0, stream>>>(hidden, hbf, (long)NA * D / 4);
  dim3 tb(32, 8);
  k_transpose_bf16<<<dim3(H / 32, D / 32), tb, 0, stream>>>(fW1, w1tf, D, H);
  k_transpose_bf16<<<dim3(H / 32, D / 32), tb, 0, stream>>>(wW1, w1tw, D, H);
  k_transpose_bf16<<<dim3(H / 32, H / 32), tb, 0, stream>>>(fW2, w2tf, H, H);
  k_transpose_bf16<<<dim3(H / 32, H / 32), tb, 0, stream>>>(wW2, w2tw, H, H);

  hipMemsetAsync(oacc, 0, (size_t)((char*)flag - (char*)oacc), stream);
  k_detect<<<1, 64, 0, stream>>>(seg, NA, flag);

  const int nblk = (H / 256) * (NA / 256);   // 8 * 256 = 2048
  // ffn branch
  k_gemm8<1><<<nblk, 512, 131072, stream>>>(hbf, w1tf, h1, fb1, nullptr, nullptr, H, D);
  k_gemm8<2><<<nblk, 512, 131072, stream>>>(h1, w2tf, nullptr, fb2, fW3, oacc, H, H);
  // weight branch (reuses h1)
  k_gemm8<1><<<nblk, 512, 131072, stream>>>(hbf, w1tw, h1, wb1, nullptr, nullptr, H, D);
  k_gemm8<2><<<nblk, 512, 131072, stream>>>(h1, w2tw, nullptr, wb2, wW3, wacc, H, H);

  // segment ratio + final
  k_segsum<<<NA / 256, 256, 0, stream>>>(oacc, wacc, seg, flag, fb3, wb3, osum, wsum, NA);
  k_final<<<NA / 256, 256, 0, stream>>>(oacc, wacc, seg, flag, fb3, wb3, osum, wsum, out, NA);
}